// Round 11
// baseline (1698.664 us; speedup 1.0000x reference)
//
#include <hip/hip_runtime.h>
#include <math.h>

// Program interpreter: B=1M rows, 19 steps of MLP(2->64->64->3) + argmax walk.
// fp32 emulated on f16 MFMA, 2-limb splits (lo limb scaled 2^12, RTZ pack).
//
// R11 = R8 numerics, register-dieted to fit 3 waves/SIMD (<=168 regs/wave):
//  - W1/b1, W3-diff, W3-col0 tables evicted to LDS broadcast tables
//    (q8-indexed, 4 addresses/wave, conflict-free, ~2 KB).
//  - no persistent u/c5; layer-1 recomputed directly (R8 order), c5 reloaded
//    in the epilogue.
//  - W2 limb frags stay in registers (AGPR side, MFMA-only); accs/h2p/b2v in
//    VGPRs. R10's bpermute reduce + speculation reverted (they added issue).

#define NSTEPS 19

typedef _Float16 half8   __attribute__((ext_vector_type(8)));
typedef _Float16 half2v  __attribute__((ext_vector_type(2)));
typedef float    float2v __attribute__((ext_vector_type(2)));
typedef float    float4v __attribute__((ext_vector_type(4)));

__device__ __forceinline__ half2v pkrtz(float a, float b) {
    return __builtin_bit_cast(half2v, __builtin_amdgcn_cvt_pkrtz(a, b));
}
__device__ __forceinline__ float swz_xor16(float v) {
    // BitMode: and=0x1F, or=0, xor=16 -> lane' = lane ^ 16 (within 32-group)
    int r = __builtin_amdgcn_ds_swizzle(__builtin_bit_cast(int, v), 0x401F);
    return __builtin_bit_cast(float, r);
}
__device__ __forceinline__ float2v lo2(float4v v) {
    return __builtin_shufflevector(v, v, 0, 1);
}
__device__ __forceinline__ float2v hi2(float4v v) {
    return __builtin_shufflevector(v, v, 2, 3);
}

__global__ __launch_bounds__(256, 3)
void program_kernel(const float* __restrict__ x,
                    const float* __restrict__ W1,
                    const float* __restrict__ b1,
                    const float* __restrict__ W2,
                    const float* __restrict__ b2,
                    const float* __restrict__ W3,
                    const float* __restrict__ b3,
                    float* __restrict__ out,
                    int B) {
    const int tid    = threadIdx.x;
    const int lane   = tid & 63;
    const int wave   = tid >> 6;
    const int lanelo = lane & 15;   // m: my batch row within the tile
    const int q8     = lane >> 4;   // k-slice / replica group 0..3
    const int myRow  = blockIdx.x * 64 + wave * 16 + lanelo;
    const int rowLd  = myRow < B ? myRow : (B - 1);

    // ---- LDS broadcast tables (indexed by q8; 4 addrs/wave, conflict-free)
    // TA[e][q8]  = {W1[0][k], W1[0][k+1], W1[1][k], W1[1][k+1]}, k=k(e,q8)
    // TB[i2][q8] = {b1[kb..kb+3]}
    // DD[t][c][q8] = diff-dot coefs (c=0: W3col1-col0, c=1: col2-col0), n0..n0+3
    // W30[t][q8]   = {W3[n*3+0]}, n0..n0+3
    __shared__ float4 TA[8][4];
    __shared__ float4 TB[4][4];
    __shared__ float4 DD[4][2][4];
    __shared__ float4 W30[4][4];
    if (tid < 96) {
        if (tid < 32) {
            const int e = tid >> 2, q = tid & 3;
            const int k = (e >> 2) * 32 + q * 8 + (e & 3) * 2;
            TA[e][q] = make_float4(W1[k], W1[k + 1], W1[64 + k], W1[64 + k + 1]);
        } else if (tid < 48) {
            const int j = tid - 32;
            const int i2 = j >> 2, q = j & 3;
            const int kb = (i2 >> 1) * 32 + q * 8 + (i2 & 1) * 4;
            TB[i2][q] = make_float4(b1[kb], b1[kb + 1], b1[kb + 2], b1[kb + 3]);
        } else if (tid < 80) {
            const int j = tid - 48;
            const int t = j >> 3, c = (j >> 2) & 1, q = j & 3;
            const int n0 = 16 * t + 4 * q;
            const int cc = c + 1;
            DD[t][c][q] = make_float4(
                W3[(n0 + 0) * 3 + cc] - W3[(n0 + 0) * 3],
                W3[(n0 + 1) * 3 + cc] - W3[(n0 + 1) * 3],
                W3[(n0 + 2) * 3 + cc] - W3[(n0 + 2) * 3],
                W3[(n0 + 3) * 3 + cc] - W3[(n0 + 3) * 3]);
        } else {
            const int j = tid - 80;
            const int t = j >> 2, q = j & 3;
            const int n0 = 16 * t + 4 * q;
            W30[t][q] = make_float4(W3[n0 * 3], W3[(n0 + 1) * 3],
                                    W3[(n0 + 2) * 3], W3[(n0 + 3) * 3]);
        }
    }
    __syncthreads();

    // ---- W2^T limb A-frags (MFMA-only; AGPR side) ----
    half8 Wh[2][4], Wl[2][4];
    #pragma unroll
    for (int kf = 0; kf < 2; ++kf) {
        #pragma unroll
        for (int t = 0; t < 4; ++t) {
            half8 bh, bl;
            #pragma unroll
            for (int j = 0; j < 8; ++j) {
                const float w =
                    W2[(kf * 32 + q8 * 8 + j) * 64 + t * 16 + lanelo];
                const _Float16 wh = (_Float16)w;                       // RNE
                const _Float16 wl = (_Float16)((w - (float)wh) * 4096.0f);
                bh[j] = wh;
                bl[j] = wl;
            }
            Wh[kf][t] = bh;
            Wl[kf][t] = bl;
        }
    }

    // ---- b2 pairs for the combine (VGPR, 8 regs): n = 16t + 4*q8 + r ----
    float2v b2v[8];
    #pragma unroll
    for (int t = 0; t < 4; ++t) {
        const int n = t * 16 + q8 * 4;
        b2v[2 * t]     = (float2v){b2[n],     b2[n + 1]};
        b2v[2 * t + 1] = (float2v){b2[n + 2], b2[n + 3]};
    }
    const float b3v0 = b3[0];
    const float db10 = b3[1] - b3[0];
    const float db20 = b3[2] - b3[0];

    // ---- initial row state (4x replicated across q8 groups) ----
    float pos, fwd;
    {
        const float2* xr = (const float2*)(x + (size_t)rowLd * 6);
        const float2 a = xr[0];
        pos = a.x;
        fwd = a.y;
    }

    const float4v zf = {0.f, 0.f, 0.f, 0.f};
    const float2v z2 = {0.f, 0.f};
    const float2v kinv = {1.0f / 4096.0f, 1.0f / 4096.0f};
    float g10 = 0.f, g20 = 0.f;
    float2v h2p[8];

    #pragma unroll 1
    for (int step = 0; step < NSTEPS; ++step) {
        // ---- layer 1 (R8 order) + 2-limb split -> B-frag limbs ----
        const float2v posp = {pos, pos}, fwdp = {fwd, fwd};
        half8 Hh[2], Hl[2];
        #pragma unroll
        for (int kf = 0; kf < 2; ++kf) {
            union { half8 v; half2v h2[4]; } uh, ul;
            #pragma unroll
            for (int p = 0; p < 4; ++p) {
                const int e = kf * 4 + p;
                const float4 ta = TA[e][q8];
                const float4 tb = TB[e >> 1][q8];
                const float2v w1ae = {ta.x, ta.y};
                const float2v w1be = {ta.z, ta.w};
                const float2v b1e  = (e & 1) ? (float2v){tb.z, tb.w}
                                             : (float2v){tb.x, tb.y};
                float2v z = __builtin_elementwise_fma(fwdp, w1be, b1e);
                z = __builtin_elementwise_fma(posp, w1ae, z);
                const float2v hp = __builtin_elementwise_max(z, z2);
                uh.h2[p] = pkrtz(hp[0], hp[1]);
                const float r0 = fmaf((float)uh.h2[p][0], -1.0f, hp[0]);
                const float r1 = fmaf((float)uh.h2[p][1], -1.0f, hp[1]);
                const float2v rp = (float2v){r0, r1} * 4096.0f;
                ul.h2[p] = pkrtz(rp[0], rp[1]);
            }
            Hh[kf] = uh.v;
            Hl[kf] = ul.v;
        }

        // ---- layer 2 via MFMA (R8-exact chains; zero C-inits) ----
        float4v accA[4], accB[4];
        #pragma unroll
        for (int t = 0; t < 4; ++t) {
            accB[t] = __builtin_amdgcn_mfma_f32_16x16x32_f16(
                Wl[0][t], Hh[0], zf, 0, 0, 0);
            accB[t] = __builtin_amdgcn_mfma_f32_16x16x32_f16(
                Wh[0][t], Hl[0], accB[t], 0, 0, 0);
            accB[t] = __builtin_amdgcn_mfma_f32_16x16x32_f16(
                Wl[1][t], Hh[1], accB[t], 0, 0, 0);
            accB[t] = __builtin_amdgcn_mfma_f32_16x16x32_f16(
                Wh[1][t], Hl[1], accB[t], 0, 0, 0);
            accA[t] = __builtin_amdgcn_mfma_f32_16x16x32_f16(
                Wh[0][t], Hh[0], zf, 0, 0, 0);
            accA[t] = __builtin_amdgcn_mfma_f32_16x16x32_f16(
                Wh[1][t], Hh[1], accA[t], 0, 0, 0);
        }

        // ---- combine (R8-exact): h2 = relu((accA + b2) + accB/4096) ----
        #pragma unroll
        for (int t = 0; t < 4; ++t) {
            const float2v alo = lo2(accA[t]) + b2v[2 * t];
            const float2v ahi = hi2(accA[t]) + b2v[2 * t + 1];
            h2p[2 * t] = __builtin_elementwise_max(
                __builtin_elementwise_fma(lo2(accB[t]), kinv, alo), z2);
            h2p[2 * t + 1] = __builtin_elementwise_max(
                __builtin_elementwise_fma(hi2(accB[t]), kinv, ahi), z2);
        }

        // ---- difference dots (R8-exact single chains, d from LDS) ----
        float2v s1 = z2, s2 = z2;
        #pragma unroll
        for (int t = 0; t < 4; ++t) {
            const float4 d1 = DD[t][0][q8];
            const float4 d2 = DD[t][1][q8];
            s1 = __builtin_elementwise_fma(h2p[2 * t], (float2v){d1.x, d1.y}, s1);
            s1 = __builtin_elementwise_fma(h2p[2 * t + 1], (float2v){d1.z, d1.w}, s1);
            s2 = __builtin_elementwise_fma(h2p[2 * t], (float2v){d2.x, d2.y}, s2);
            s2 = __builtin_elementwise_fma(h2p[2 * t + 1], (float2v){d2.z, d2.w}, s2);
        }
        float t1 = s1[0] + s1[1];
        float t2 = s2[0] + s2[1];

        // ---- butterfly cross-replica reduce (R8-exact) ----
        t1 += swz_xor16(t1);
        t2 += swz_xor16(t2);
        t1 += __shfl_xor(t1, 32, 64);
        t2 += __shfl_xor(t2, 32, 64);
        g10 = t1 + db10;   // = l1 - l0
        g20 = t2 + db20;   // = l2 - l0

        // ---- decision: first-max-wins argmax via logit diffs ----
        const float delta =
            (g20 > fmaxf(0.f, g10)) ? 1.0f : ((g10 > 0.f) ? 0.0f : -1.0f);
        pos += delta;
        fwd += 1.0f;
    }

    // ---- reconstruct full logits from the last step's h2p ----
    float l0, l1, l2;
    {
        float2v s0 = z2;
        #pragma unroll
        for (int t = 0; t < 4; ++t) {
            const float4 w0 = W30[t][q8];
            s0 = __builtin_elementwise_fma(h2p[2 * t], (float2v){w0.x, w0.y}, s0);
            s0 = __builtin_elementwise_fma(h2p[2 * t + 1], (float2v){w0.z, w0.w}, s0);
        }
        float t0 = s0[0] + s0[1];
        t0 += swz_xor16(t0);
        t0 += __shfl_xor(t0, 32, 64);
        l0 = t0 + b3v0;
        l1 = l0 + g10;
        l2 = l0 + g20;
    }

    // ---- epilogue: q8==0 lanes store ----
    if (q8 == 0 && myRow < B) {
        const float c5 = x[(size_t)rowLd * 6 + 5];
        const float p0 = 1.f / (1.f + __expf(-l0));
        const float p1 = 1.f / (1.f + __expf(-l1));
        const float p2 = 1.f / (1.f + __expf(-l2));
        float2* o = (float2*)(out + (size_t)myRow * 6);
        o[0] = make_float2(pos, fwd);
        o[1] = make_float2(p0, p1);
        o[2] = make_float2(p2, c5 + (float)NSTEPS);
    }
}

extern "C" void kernel_launch(void* const* d_in, const int* in_sizes, int n_in,
                              void* d_out, int out_size, void* d_ws, size_t ws_size,
                              hipStream_t stream) {
    const float* x  = (const float*)d_in[0];
    const float* W1 = (const float*)d_in[1];
    const float* b1 = (const float*)d_in[2];
    const float* W2 = (const float*)d_in[3];
    const float* b2 = (const float*)d_in[4];
    const float* W3 = (const float*)d_in[5];
    const float* b3 = (const float*)d_in[6];
    float* out = (float*)d_out;

    const int B = in_sizes[0] / 6;              // 1048576
    const int nBlocks = (B + 63) / 64;          // 64 rows/block (4 waves x 16)

    program_kernel<<<nBlocks, 256, 0, stream>>>(
        x, W1, b1, W2, b2, W3, b3, out, B);
}